// Round 6
// baseline (261.993 us; speedup 1.0000x reference)
//
#include <hip/hip_runtime.h>

// Geometry (fixed by reference)
#define NTOK 197
#define NHEADS 12
#define DIM 768
#define PP 20
#define KK 5
#define STOT 397
#define BB 128
#define NIMG 196
#define NGRP 394                 // 392 img groups + 2 cls groups (64 tokens each)
#define NCHUNK 6
#define CHUNK 128
#define PCH 24                   // padded partial slots per token (20 acc + xsq + pad)
#define NALLTOK (BB * NTOK)      // 25216
#define HSTRIDE (NTOK * STOT)    // 78209

static const long long MASK_ELEMS = (long long)BB * NHEADS * NTOK * STOT; // 120129024

typedef float float4b __attribute__((ext_vector_type(4), aligned(16)));

// ---------------- Kernel 1: inverse norms of the 40 keys at `layer` -------------
__global__ void knorm_kernel(const float* __restrict__ kc,
                             const float* __restrict__ ki,
                             const int* __restrict__ layer_p,
                             float* __restrict__ invn /*40 floats*/) {
    int layer = *layer_p;
    int kid = blockIdx.x;              // 0..39 ; 0-19 cls, 20-39 img
    const float* base = (kid < PP ? kc : ki) + (size_t)layer * PP * DIM;
    const float* kp = base + (size_t)(kid % PP) * DIM;
    int lane = threadIdx.x;            // 64 threads
    float s = 0.f;
    for (int i = lane; i < DIM; i += 64) { float v = kp[i]; s += v * v; }
    #pragma unroll
    for (int m = 1; m < 64; m <<= 1) s += __shfl_xor(s, m, 64);
    if (lane == 0) invn[kid] = 1.0f / fmaxf(sqrtf(s), 1e-12f);
}

// ---------------- Kernel 2: partial dots, chunk-split ---------------------------
// 2364 blocks x 64 threads: block = (token-group g, chunk c). 64 tokens per group,
// 128 dims per chunk. Writes 21 coalesced partials per token.
__global__ __launch_bounds__(64) void route_part_kernel(
        const float* __restrict__ x,
        const float* __restrict__ kc,
        const float* __restrict__ ki,
        const int* __restrict__ layer_p,
        float* __restrict__ part /* [6][PCH][25216] */) {
    const int blk = blockIdx.x;        // 0..2363
    const int g = blk / NCHUNK;        // 0..393
    const int c = blk - g * NCHUNK;    // 0..5
    const int lane = threadIdx.x;      // 0..63
    const bool is_cls = (g >= 392);
    const int layer = __builtin_amdgcn_readfirstlane(*layer_p);

    __shared__ float xs[64 * 132];     // 33,792 B (pitch 132 keeps starts spread)
    __shared__ float ks[PP * CHUNK];   // 10,240 B (uniform reads: no conflicts)
    __shared__ int rowoff[64];

    int tok;
    if (!is_cls) {
        int i = g * 64 + lane;                     // 0..25087
        int b = i / NIMG;
        int t = i - b * NIMG;
        tok = b * NTOK + 1 + t;
    } else {
        int b = (g - 392) * 64 + lane;             // 0..127
        tok = b * NTOK;
    }
    rowoff[lane] = tok * DIM + c * CHUNK;
    const float* __restrict__ kb =
        (is_cls ? kc : ki) + (size_t)layer * PP * DIM + c * CHUNK;
    __syncthreads();

    // stage keys chunk: 20 rows x 32 float4
    #pragma unroll
    for (int ps = 0; ps < 10; ++ps) {
        int idx = ps * 64 + lane;
        int kr = idx >> 5, f4 = idx & 31;
        *(float4b*)&ks[kr * CHUNK + f4 * 4] = *(const float4b*)(kb + kr * DIM + f4 * 4);
    }
    // stage x chunk: 64 rows x 32 float4 (coalesced 512B runs)
    #pragma unroll 8
    for (int ps = 0; ps < 32; ++ps) {
        int idx = ps * 64 + lane;
        int r = idx >> 5, f4 = idx & 31;
        *(float4b*)&xs[r * 132 + f4 * 4] = *(const float4b*)(x + rowoff[r] + f4 * 4);
    }
    __syncthreads();

    float acc[PP];
    #pragma unroll
    for (int p = 0; p < PP; ++p) acc[p] = 0.f;
    float xsq = 0.f;

    #pragma unroll 2
    for (int q = 0; q < 32; ++q) {
        float4b xv = *(const float4b*)&xs[lane * 132 + q * 4];
        xsq += xv.x * xv.x + xv.y * xv.y + xv.z * xv.z + xv.w * xv.w;
        #pragma unroll
        for (int p = 0; p < PP; ++p) {
            float4b kv = *(const float4b*)&ks[p * CHUNK + q * 4];  // uniform bcast
            acc[p] += xv.x * kv.x + xv.y * kv.y + xv.z * kv.z + xv.w * kv.w;
        }
    }

    const int slot = g * 64 + lane;    // 0..25215
    float* pp = part + (size_t)(c * PCH) * NALLTOK + slot;
    #pragma unroll
    for (int p = 0; p < PP; ++p) pp[(size_t)p * NALLTOK] = acc[p];   // coalesced
    pp[(size_t)PP * NALLTOK] = xsq;
}

// ---------------- Kernel 3: combine partials + top-5 ----------------------------
// 394 blocks x 64 threads, one token per lane.
__global__ __launch_bounds__(64) void combine_kernel(
        const float* __restrict__ part,
        const float* __restrict__ invn,
        int* __restrict__ bits_ws,      /* [25216] */
        float* __restrict__ dist_part   /* [394]   */) {
    const int g = blockIdx.x;
    const int lane = threadIdx.x;
    const bool is_cls = (g >= 392);
    const int slot = g * 64 + lane;

    int tok;
    if (!is_cls) {
        int i = slot;
        int b = i / NIMG;
        int t = i - b * NIMG;
        tok = b * NTOK + 1 + t;
    } else {
        int b = slot - 25088;
        tok = b * NTOK;
    }

    float acc[PP + 1];
    #pragma unroll
    for (int p = 0; p <= PP; ++p) acc[p] = 0.f;
    #pragma unroll
    for (int c = 0; c < NCHUNK; ++c) {
        #pragma unroll
        for (int p = 0; p <= PP; ++p)
            acc[p] += part[(size_t)(c * PCH + p) * NALLTOK + slot];  // coalesced
    }

    const float* ik = invn + (is_cls ? 0 : PP);
    float invx = 1.0f / fmaxf(sqrtf(acc[PP]), 1e-12f);
    float sims[PP];
    #pragma unroll
    for (int p = 0; p < PP; ++p) sims[p] = acc[p] * invx * ik[p];

    int bits = 0; float sum5 = 0.f;
    #pragma unroll
    for (int j = 0; j < KK; ++j) {
        int bi = 0; float bv = -3.0e38f;
        #pragma unroll
        for (int p = 0; p < PP; ++p) {
            bool ok = !((bits >> p) & 1) && (sims[p] > bv);
            bv = ok ? sims[p] : bv;
            bi = ok ? p : bi;
        }
        bits |= (1 << bi);
        sum5 += bv;
    }
    bits_ws[tok] = bits;

    float dist = (float)KK - sum5;
    #pragma unroll
    for (int m = 1; m < 64; m <<= 1) dist += __shfl_xor(dist, m, 64);
    if (lane == 0) dist_part[g] = dist;
}

// ---------------- Kernel 4: contiguous-image mask writer ------------------------
// 1536 blocks x 256 threads: block = (b,h), writes its 312KB image sequentially.
__global__ __launch_bounds__(256) void write_kernel(
        const int* __restrict__ bits_ws,
        float* __restrict__ out) {
    const int bh = blockIdx.x;          // 0..1535 = b*12+h
    const int b = bh / NHEADS;
    const int* __restrict__ bb = bits_ws + b * NTOK;
    const int tid = threadIdx.x;
    const int s1 = tid;                 // 0..255
    const int s2 = tid + 256;           // 256..511
    const bool act2 = (s2 < STOT);      // s2 >= 201 always -> value 1.0

    // per-thread column templates (computed once)
    const bool var_i = (s1 >= 101) & (s1 <= 200);
    const int  q_i   = var_i ? (s1 - 101) / 5 : 0;
    const bool var_c = (s1 >= 1) & (s1 <= 100);
    const int  q_c   = var_c ? (s1 - 1) / 5 : 0;
    const float base1 = ((s1 == 0) | (s1 >= 201)) ? 1.f : 0.f;

    float* dst = out + (size_t)bh * HSTRIDE;

    // t = 0 (cls row)
    {
        int w = bb[0];
        float v = var_c ? (float)((w >> q_c) & 1) : base1;
        dst[s1] = v;
        if (act2) dst[s2] = 1.f;
        dst += STOT;
    }
    // t = 1..196 (img rows)
    #pragma unroll 4
    for (int t = 1; t < NTOK; ++t) {
        int w = bb[t];
        float v = var_i ? (float)((w >> q_i) & 1) : base1;
        dst[s1] = v;
        if (act2) dst[s2] = 1.f;
        dst += STOT;
    }
}

// ---------------- Kernel 5: tiny final dist reduce ------------------------------
__global__ void reduce_kernel(const float* __restrict__ dist_part,
                              float* __restrict__ out) {
    int lane = threadIdx.x;            // 64
    float si = 0.f, sc = 0.f;
    for (int i = lane; i < 392; i += 64) si += dist_part[i];
    if (lane < 2) sc = dist_part[392 + lane];
    #pragma unroll
    for (int m = 1; m < 64; m <<= 1) {
        si += __shfl_xor(si, m, 64);
        sc += __shfl_xor(sc, m, 64);
    }
    if (lane == 0)
        out[MASK_ELEMS] = sc * (1.0f / (BB * KK)) + si * (1.0f / (BB * NIMG * KK));
}

// ---------------- launcher ------------------------------------------------------
extern "C" void kernel_launch(void* const* d_in, const int* in_sizes, int n_in,
                              void* d_out, int out_size, void* d_ws, size_t ws_size,
                              hipStream_t stream) {
    const float* x  = (const float*)d_in[0];
    const float* kc = (const float*)d_in[1];
    const float* ki = (const float*)d_in[2];
    const int* layer = (const int*)d_in[3];
    float* out = (float*)d_out;

    // small scratch in ws (proven size OK in prior rounds): invn + bits + dist
    float* invn   = (float*)d_ws;
    int*   bitsws = (int*)d_ws + 64;
    float* dpart  = (float*)d_ws + 64 + NALLTOK;

    // large partials scratch lives INSIDE out (overwritten by write_kernel later):
    // need 6*24*25216 floats = 3.63M floats; place at offset 16M floats.
    float* part = out + (size_t)(16u * 1024u * 1024u);

    knorm_kernel<<<40, 64, 0, stream>>>(kc, ki, layer, invn);
    route_part_kernel<<<NGRP * NCHUNK, 64, 0, stream>>>(x, kc, ki, layer, part);
    combine_kernel<<<NGRP, 64, 0, stream>>>(part, invn, bitsws, dpart);
    write_kernel<<<BB * NHEADS, 256, 0, stream>>>(bitsws, out);
    reduce_kernel<<<1, 64, 0, stream>>>(dpart, out);
}

// Round 7
// 229.781 us; speedup vs baseline: 1.1402x; 1.1402x over previous
//
#include <hip/hip_runtime.h>

// Geometry (fixed by reference)
#define NTOK 197
#define NHEADS 12
#define DIM 768
#define PP 20
#define KK 5
#define STOT 397
#define BB 128
#define NIMG 196
#define NALLTOK (BB * NTOK)      // 25216
#define HSTRIDE (NTOK * STOT)    // 78209

static const long long MASK_ELEMS = (long long)BB * NHEADS * NTOK * STOT; // 120129024

typedef float float4a __attribute__((ext_vector_type(4), aligned(4)));   // align-4 (out rows)
typedef float float4b __attribute__((ext_vector_type(4), aligned(16)));  // known-aligned

static __device__ __forceinline__ float dot4(float4b a, float4b b) {
    return a.x * b.x + a.y * b.y + a.z * b.z + a.w * b.w;
}

// ---------------- Kernel 1: inverse norms of the 40 keys at `layer` -------------
__global__ void knorm_kernel(const float* __restrict__ kc,
                             const float* __restrict__ ki,
                             const int* __restrict__ layer_p,
                             float* __restrict__ invn /*40 floats*/) {
    int layer = *layer_p;
    int kid = blockIdx.x;              // 0..39 ; 0-19 cls, 20-39 img
    const float* base = (kid < PP ? kc : ki) + (size_t)layer * PP * DIM;
    const float* kp = base + (size_t)(kid % PP) * DIM;
    int lane = threadIdx.x;            // 64 threads
    float s = 0.f;
    for (int i = lane; i < DIM; i += 64) { float v = kp[i]; s += v * v; }
    #pragma unroll
    for (int m = 1; m < 64; m <<= 1) s += __shfl_xor(s, m, 64);
    if (lane == 0) invn[kid] = 1.0f / fmaxf(sqrtf(s), 1e-12f);
}

// ---------------- Kernel 2: fused route + write, one 64-thr block per token -----
// R1's overlap structure (25216 blocks: LDS-route and HBM-write overlap across
// resident blocks) with the butterfly replaced by a packed LDS transpose-reduce
// and a readlane/uniform top-5.
__global__ __launch_bounds__(64) void fused_kernel(
        const float* __restrict__ x,
        const float* __restrict__ kc,
        const float* __restrict__ ki,
        const int* __restrict__ layer_p,
        const float* __restrict__ invn,
        float* __restrict__ out,
        float* __restrict__ dist_ws /* [25216] */) {
    const int bid = blockIdx.x;          // b*197 + t
    const int l = threadIdx.x;           // 0..63
    const int b = bid / NTOK;
    const int t = bid - b * NTOK;
    const bool is_cls = (t == 0);
    const int layer = *layer_p;

    const float* __restrict__ kb = (is_cls ? kc : ki) + (size_t)layer * PP * DIM;
    const float* __restrict__ xr = x + (size_t)bid * DIM;

    __shared__ float red[21 * 65 + 64];  // 21 value-rows x 65 pitch, + 64 partials

    // --- cooperative dots: lane covers dims {4l..4l+3, 256+4l.., 512+4l..} ------
    float4b xv0 = *(const float4b*)(xr + 4 * l);
    float4b xv1 = *(const float4b*)(xr + 256 + 4 * l);
    float4b xv2 = *(const float4b*)(xr + 512 + 4 * l);
    float xsq = dot4(xv0, xv0) + dot4(xv1, xv1) + dot4(xv2, xv2);

    float acc[PP];
    #pragma unroll
    for (int p = 0; p < PP; ++p) {
        const float* kp = kb + p * DIM;
        float4b k0 = *(const float4b*)(kp + 4 * l);
        float4b k1 = *(const float4b*)(kp + 256 + 4 * l);
        float4b k2 = *(const float4b*)(kp + 512 + 4 * l);
        acc[p] = dot4(xv0, k0) + dot4(xv1, k1) + dot4(xv2, k2);
    }

    // --- packed transpose-reduce: value v, lane l -> red[v*65 + l] --------------
    #pragma unroll
    for (int v = 0; v < PP; ++v) red[v * 65 + l] = acc[v];
    red[PP * 65 + l] = xsq;
    __syncthreads();

    // stage B: lane (r=l/3, seg=l%3) sums its column segment of row r
    float part = 0.f;
    if (l < 63) {
        int r = l / 3;
        int seg = l - 3 * r;
        int s0 = seg * 21 + (seg > 0 ? 1 : 0);    // {0,22,43}
        int n  = 22 - (seg > 0 ? 1 : 0);          // {22,21,21}
        const float* rr = &red[r * 65 + s0];
        #pragma unroll
        for (int i = 0; i < 22; ++i)
            if (i < n) part += rr[i];
    }
    __syncthreads();
    float* red2 = &red[21 * 65];
    if (l < 63) red2[l] = part;
    __syncthreads();

    float dotv = 0.f;
    if (l < 21) dotv = red2[3 * l] + red2[3 * l + 1] + red2[3 * l + 2];

    // lanes 0..19: scale by inv key norm; lane 20 holds xsq
    const float* __restrict__ ik = invn + (is_cls ? 0 : PP);
    float sv = dotv * ((l < PP) ? ik[l] : 1.0f);

    // monotone int mapping for float compare in integer/SALU domain
    int ibits = __float_as_int(sv);
    unsigned mu = (ibits < 0) ? ~(unsigned)ibits : ((unsigned)ibits | 0x80000000u);

    // broadcast all 21 values to uniform registers
    unsigned su[PP];
    #pragma unroll
    for (int p = 0; p < PP; ++p) su[p] = (unsigned)__builtin_amdgcn_readlane((int)mu, p);
    float xsqv = __uint_as_float((unsigned)__builtin_amdgcn_readlane(__float_as_int(dotv), PP));

    // uniform serial top-5 (strict '>' => lowest index wins ties, lax.top_k)
    unsigned bits = 0u;
    float sum5 = 0.f;
    #pragma unroll
    for (int j = 0; j < KK; ++j) {
        unsigned best = 0u; int bidx = 0;
        #pragma unroll
        for (int p = 0; p < PP; ++p) {
            bool ok = !((bits >> p) & 1u) && (su[p] > best);
            best = ok ? su[p] : best;
            bidx = ok ? p : bidx;
        }
        bits |= (1u << bidx);
        unsigned fb = (best & 0x80000000u) ? (best & 0x7FFFFFFFu) : ~best;
        sum5 += __uint_as_float(fb);
    }
    float invx = 1.0f / fmaxf(sqrtf(xsqv), 1e-12f);
    if (l == 0) dist_ws[bid] = (float)KK - sum5 * invx;

    // --- write phase: 12 head-rows of 397 floats (cols >= 256 are all 1.0) ------
    const int lo = is_cls ? 1 : 101;
    float4a v0;
    #pragma unroll
    for (int k = 0; k < 4; ++k) {
        int s = 4 * l + k;
        unsigned d = (unsigned)(s - lo);
        bool inw = d < 100u;
        unsigned q = d / 5u;
        float vv = ((s == 0) | (s >= 201)) ? 1.f
                 : (inw ? (float)((bits >> q) & 1u) : 0.f);
        v0[k] = vv;
    }
    float4a ones = {1.f, 1.f, 1.f, 1.f};

    #pragma unroll
    for (int h = 0; h < NHEADS; ++h) {
        float* d0 = out + ((size_t)(b * NHEADS + h) * NTOK + t) * (size_t)STOT;
        *(float4a*)(d0 + 4 * l) = v0;                       // cols 0..255
        if (l < 35)      *(float4a*)(d0 + 256 + 4 * l) = ones;  // cols 256..395
        else if (l == 35) d0[396] = 1.0f;                   // col 396
    }
}

// ---------------- Kernel 3: dist reduce over 25216 tokens -----------------------
__global__ __launch_bounds__(256) void reduce_kernel(
        const float* __restrict__ dist_ws,
        float* __restrict__ out) {
    const int tid = threadIdx.x;   // single block, 256 threads
    float sc = 0.f, si = 0.f;
    for (int i = tid; i < NALLTOK; i += 256) {
        unsigned q = (unsigned)i / 197u;
        unsigned r = (unsigned)i - q * 197u;
        float v = dist_ws[i];
        if (r == 0) sc += v; else si += v;
    }
    #pragma unroll
    for (int m = 1; m < 64; m <<= 1) {
        sc += __shfl_xor(sc, m, 64);
        si += __shfl_xor(si, m, 64);
    }
    __shared__ float lc[4], li[4];
    int lane = tid & 63, wv = tid >> 6;
    if (lane == 0) { lc[wv] = sc; li[wv] = si; }
    __syncthreads();
    if (tid == 0) {
        float c = lc[0] + lc[1] + lc[2] + lc[3];
        float i = li[0] + li[1] + li[2] + li[3];
        out[MASK_ELEMS] = c / (float)(BB * KK) + i / (float)(BB * NIMG * KK);
    }
}

// ---------------- launcher ------------------------------------------------------
extern "C" void kernel_launch(void* const* d_in, const int* in_sizes, int n_in,
                              void* d_out, int out_size, void* d_ws, size_t ws_size,
                              hipStream_t stream) {
    const float* x  = (const float*)d_in[0];
    const float* kc = (const float*)d_in[1];
    const float* ki = (const float*)d_in[2];
    const int* layer = (const int*)d_in[3];
    float* out = (float*)d_out;

    // ws: [0..64) invnorms, [64..64+25216) per-token dist
    float* invn    = (float*)d_ws;
    float* dist_ws = (float*)d_ws + 64;

    knorm_kernel<<<40, 64, 0, stream>>>(kc, ki, layer, invn);
    fused_kernel<<<NALLTOK, 64, 0, stream>>>(x, kc, ki, layer, invn, out, dist_ws);
    reduce_kernel<<<1, 256, 0, stream>>>(dist_ws, out);
}

// Round 8
// 209.640 us; speedup vs baseline: 1.2497x; 1.0961x over previous
//
#include <hip/hip_runtime.h>

// Geometry (fixed by reference)
#define NTOK 197
#define NHEADS 12
#define DIM 768
#define PP 20
#define KK 5
#define STOT 397
#define BB 128
#define NIMG 196
#define NALLTOK (BB * NTOK)      // 25216
#define HSTRIDE (NTOK * STOT)    // 78209

static const long long MASK_ELEMS = (long long)BB * NHEADS * NTOK * STOT; // 120129024

typedef float float4b __attribute__((ext_vector_type(4), aligned(16)));

static __device__ __forceinline__ float dot4(float4b a, float4b b) {
    return a.x * b.x + a.y * b.y + a.z * b.z + a.w * b.w;
}

// ---------------- Kernel 1: inverse norms of the 40 keys at `layer` -------------
__global__ void knorm_kernel(const float* __restrict__ kc,
                             const float* __restrict__ ki,
                             const int* __restrict__ layer_p,
                             float* __restrict__ invn /*40 floats*/) {
    int layer = *layer_p;
    int kid = blockIdx.x;              // 0..39 ; 0-19 cls, 20-39 img
    const float* base = (kid < PP ? kc : ki) + (size_t)layer * PP * DIM;
    const float* kp = base + (size_t)(kid % PP) * DIM;
    int lane = threadIdx.x;            // 64 threads
    float s = 0.f;
    for (int i = lane; i < DIM; i += 64) { float v = kp[i]; s += v * v; }
    #pragma unroll
    for (int m = 1; m < 64; m <<= 1) s += __shfl_xor(s, m, 64);
    if (lane == 0) invn[kid] = 1.0f / fmaxf(sqrtf(s), 1e-12f);
}

// ---------------- Kernel 2: fused route + write ---------------------------------
// 25216 blocks x 256 threads (32 waves/CU). Wave w computes full-768 dots for
// keys 5w..5w+4 (5 values/wave -> <=36 swizzles), 21 partials meet in a 24-float
// LDS array, every wave redundantly runs the uniform readlane top-5, then the
// block streams 12 head-rows with ALIGNED coalesced scalar NT stores.
__global__ __launch_bounds__(256) void fused_kernel(
        const float* __restrict__ x,
        const float* __restrict__ kc,
        const float* __restrict__ ki,
        const int* __restrict__ layer_p,
        const float* __restrict__ invn,
        float* __restrict__ out,
        float* __restrict__ dist_ws /* [25216] */) {
    const int bid = blockIdx.x;          // b*197 + t
    const int tid = threadIdx.x;
    const int l = tid & 63;
    const int w = tid >> 6;              // wave 0..3
    const int b = bid / NTOK;
    const int t = bid - b * NTOK;
    const bool is_cls = (t == 0);
    const int layer = *layer_p;

    const float* __restrict__ kb = (is_cls ? kc : ki) + (size_t)layer * PP * DIM;
    const float* __restrict__ xr = x + (size_t)bid * DIM;

    __shared__ float vals[24];           // 21 used

    // --- x row fragment: dims {4l..4l+3, 256+4l.., 512+4l..} (1KB/instr) --------
    float4b xv0 = *(const float4b*)(xr + 4 * l);
    float4b xv1 = *(const float4b*)(xr + 256 + 4 * l);
    float4b xv2 = *(const float4b*)(xr + 512 + 4 * l);

    // --- 5 keys for this wave, full 768-dim partial dots ------------------------
    float acc[5];
    #pragma unroll
    for (int j = 0; j < 5; ++j) {
        const float* kp = kb + (size_t)(5 * w + j) * DIM;
        float4b k0 = *(const float4b*)(kp + 4 * l);
        float4b k1 = *(const float4b*)(kp + 256 + 4 * l);
        float4b k2 = *(const float4b*)(kp + 512 + 4 * l);
        acc[j] = dot4(xv0, k0) + dot4(xv1, k1) + dot4(xv2, k2);
    }
    // butterfly: 5 values everywhere, +xsq on wave 0 only
    #pragma unroll
    for (int m = 1; m < 64; m <<= 1) {
        #pragma unroll
        for (int j = 0; j < 5; ++j) acc[j] += __shfl_xor(acc[j], m, 64);
    }
    if (w == 0) {
        float xsq = dot4(xv0, xv0) + dot4(xv1, xv1) + dot4(xv2, xv2);
        #pragma unroll
        for (int m = 1; m < 64; m <<= 1) xsq += __shfl_xor(xsq, m, 64);
        if (l == 0) vals[PP] = xsq;
    }
    if (l == 0) {
        #pragma unroll
        for (int j = 0; j < 5; ++j) vals[5 * w + j] = acc[j];
    }
    __syncthreads();

    // --- uniform top-5 (per wave, redundant): readlane + monotone-int compare ---
    float dotv = vals[l < 21 ? l : 20];
    float ikl = (l < PP) ? invn[(is_cls ? 0 : PP) + l] : 1.0f;
    float sv = dotv * ikl;               // invx>0 applied later: order-preserving
    int ib = __float_as_int(sv);
    unsigned mu = (ib < 0) ? ~(unsigned)ib : ((unsigned)ib | 0x80000000u);

    unsigned su[PP];
    #pragma unroll
    for (int p = 0; p < PP; ++p) su[p] = (unsigned)__builtin_amdgcn_readlane((int)mu, p);
    float xsqv = __uint_as_float((unsigned)__builtin_amdgcn_readlane(__float_as_int(dotv), PP));

    unsigned bits = 0u;
    float sum5 = 0.f;
    #pragma unroll
    for (int j = 0; j < KK; ++j) {
        unsigned best = 0u; int bidx = 0;
        #pragma unroll
        for (int p = 0; p < PP; ++p) {
            bool ok = !((bits >> p) & 1u) && (su[p] > best);
            best = ok ? su[p] : best;
            bidx = ok ? p : bidx;
        }
        bits |= (1u << bidx);
        unsigned fb = (best & 0x80000000u) ? (best & 0x7FFFFFFFu) : ~best;
        sum5 += __uint_as_float(fb);
    }
    float invx = 1.0f / fmaxf(sqrtf(xsqv), 1e-12f);
    if (tid == 0) dist_ws[bid] = (float)KK - sum5 * invx;

    // --- write: 12 head-rows; cols tid and tid+256; aligned scalar NT stores ----
    const int lo = is_cls ? 1 : 101;
    unsigned d = (unsigned)(tid - lo);
    bool inw = d < 100u;
    unsigned q = d / 5u;
    float v1 = ((tid == 0) | (tid >= 201)) ? 1.f
             : (inw ? (float)((bits >> q) & 1u) : 0.f);
    const bool act2 = tid < (STOT - 256);      // 141 threads
    float* base = out + ((size_t)(b * NHEADS) * NTOK + t) * (size_t)STOT;
    #pragma unroll
    for (int h = 0; h < NHEADS; ++h) {
        float* d0 = base + (size_t)h * HSTRIDE;
        __builtin_nontemporal_store(v1, d0 + tid);
        if (act2) __builtin_nontemporal_store(1.0f, d0 + tid + 256);
    }
}

// ---------------- Kernel 3: dist reduce over 25216 tokens -----------------------
__global__ __launch_bounds__(256) void reduce_kernel(
        const float* __restrict__ dist_ws,
        float* __restrict__ out) {
    const int tid = threadIdx.x;   // single block, 256 threads
    float sc = 0.f, si = 0.f;
    for (int i = tid; i < NALLTOK; i += 256) {
        unsigned qq = (unsigned)i / 197u;
        unsigned r = (unsigned)i - qq * 197u;
        float v = dist_ws[i];
        if (r == 0) sc += v; else si += v;
    }
    #pragma unroll
    for (int m = 1; m < 64; m <<= 1) {
        sc += __shfl_xor(sc, m, 64);
        si += __shfl_xor(si, m, 64);
    }
    __shared__ float lc[4], li[4];
    int lane = tid & 63, wv = tid >> 6;
    if (lane == 0) { lc[wv] = sc; li[wv] = si; }
    __syncthreads();
    if (tid == 0) {
        float c = lc[0] + lc[1] + lc[2] + lc[3];
        float i = li[0] + li[1] + li[2] + li[3];
        out[MASK_ELEMS] = c / (float)(BB * KK) + i / (float)(BB * NIMG * KK);
    }
}

// ---------------- launcher ------------------------------------------------------
extern "C" void kernel_launch(void* const* d_in, const int* in_sizes, int n_in,
                              void* d_out, int out_size, void* d_ws, size_t ws_size,
                              hipStream_t stream) {
    const float* x  = (const float*)d_in[0];
    const float* kc = (const float*)d_in[1];
    const float* ki = (const float*)d_in[2];
    const int* layer = (const int*)d_in[3];
    float* out = (float*)d_out;

    // ws: [0..64) invnorms, [64..64+25216) per-token dist
    float* invn    = (float*)d_ws;
    float* dist_ws = (float*)d_ws + 64;

    knorm_kernel<<<40, 64, 0, stream>>>(kc, ki, layer, invn);
    fused_kernel<<<NALLTOK, 256, 0, stream>>>(x, kc, ki, layer, invn, out, dist_ws);
    reduce_kernel<<<1, 256, 0, stream>>>(dist_ws, out);
}